// Round 1
// baseline (59312.817 us; speedup 1.0000x reference)
//
#include <hip/hip_runtime.h>
#include <cstddef>

#define U_DIM 512
#define T_DIM 2048
#define B_DIM 32
#define F_DIM 1024
#define M_DIM (B_DIM * T_DIM)

// ---------------------------------------------------------------------------
// GEMM: potentials[m][n] = sum_k x[m][k]*W[k][n] + b[n] (+ boundary at t=0/T-1)
// fp32 vector-ALU (no fp32 MFMA on CDNA4). 128x64 tile, 256 threads, 8x4 micro.
// ---------------------------------------------------------------------------
#define BM 128
#define BN 64
#define BK 16

__global__ __launch_bounds__(256) void gemm_kernel(
    const float* __restrict__ x, const float* __restrict__ W,
    const float* __restrict__ bias, const float* __restrict__ lb,
    const float* __restrict__ rb, float* __restrict__ out)
{
  __shared__ float As[BK][BM + 4];   // +4 pad keeps 16B align, breaks conflicts
  __shared__ float Bs[BK][BN];
  const int m0 = blockIdx.x * BM;
  const int n0 = blockIdx.y * BN;
  const int tid = threadIdx.x;
  const int tx = tid & 15;   // N direction (16 x 4 = 64)
  const int ty = tid >> 4;   // M direction (16 x 8 = 128)

  float acc[8][4];
#pragma unroll
  for (int i = 0; i < 8; ++i)
#pragma unroll
    for (int j = 0; j < 4; ++j) acc[i][j] = 0.f;

  for (int k0 = 0; k0 < F_DIM; k0 += BK) {
    // stage A tile (128x16), transposed into As[k][m]
#pragma unroll
    for (int i = 0; i < 2; ++i) {
      int id = i * 256 + tid;          // 0..511 float4 slots
      int row = id >> 2;               // 0..127
      int c4 = (id & 3) << 2;          // 0,4,8,12
      float4 a = *(const float4*)(x + (size_t)(m0 + row) * F_DIM + k0 + c4);
      As[c4 + 0][row] = a.x;
      As[c4 + 1][row] = a.y;
      As[c4 + 2][row] = a.z;
      As[c4 + 3][row] = a.w;
    }
    // stage B tile (16x64)
    {
      int krow = tid >> 4;
      int c4 = (tid & 15) << 2;
      *(float4*)(&Bs[krow][c4]) =
          *(const float4*)(W + (size_t)(k0 + krow) * U_DIM + n0 + c4);
    }
    __syncthreads();
#pragma unroll
    for (int k = 0; k < BK; ++k) {
      float a[8], bb[4];
#pragma unroll
      for (int i = 0; i < 8; ++i) a[i] = As[k][ty * 8 + i];
#pragma unroll
      for (int j = 0; j < 4; ++j) bb[j] = Bs[k][tx * 4 + j];
#pragma unroll
      for (int i = 0; i < 8; ++i)
#pragma unroll
        for (int j = 0; j < 4; ++j) acc[i][j] += a[i] * bb[j];
    }
    __syncthreads();
  }

  // epilogue: + bias, + left boundary at t==0, + right boundary at t==T-1
#pragma unroll
  for (int i = 0; i < 8; ++i) {
    int m = m0 + ty * 8 + i;
    int t = m & (T_DIM - 1);
    float4 o;
#pragma unroll
    for (int j = 0; j < 4; ++j) {
      int n = n0 + tx * 4 + j;
      float v = acc[i][j] + bias[n];
      if (t == 0) v += lb[n];
      if (t == T_DIM - 1) v += rb[n];
      ((float*)&o)[j] = v;
    }
    *(float4*)(out + (size_t)m * U_DIM + n0 + tx * 4) = o;
  }
}

// ---------------------------------------------------------------------------
// aux: copy transitions to output tail, build transposed TrT[u][v] in ws,
// write sequence_lengths (=2048.0f).
// ---------------------------------------------------------------------------
__global__ void aux_kernel(const float* __restrict__ tr, float* __restrict__ out_tr,
                           float* __restrict__ trT, float* __restrict__ seqlen)
{
  int idx = blockIdx.x * blockDim.x + threadIdx.x;
  if (idx < U_DIM * U_DIM) {
    float v = tr[idx];
    out_tr[idx] = v;
    int r = idx >> 9;   // v index
    int c = idx & 511;  // u index
    trT[(size_t)c * U_DIM + r] = v;
  }
  if (idx < B_DIM) seqlen[idx] = (float)T_DIM;
}

// ---------------------------------------------------------------------------
// Viterbi forward scan + backtrack. One workgroup per batch, 1024 threads:
// thread = (u = tid&511, vb = tid>>9). Each thread reduces 256 v's of TrT
// row u; partials combined in LDS. Backpointers stored as u16 in ws.
// Tie-break: ascending v with strict '>' == jnp.argmax first-max semantics.
// ---------------------------------------------------------------------------
__global__ __launch_bounds__(1024) void scan_kernel(
    const float* __restrict__ pot, const float* __restrict__ trT,
    unsigned short* __restrict__ bp, float* __restrict__ outv)
{
  const int b = blockIdx.x;
  const int tid = threadIdx.x;
  const int u = tid & 511;
  const int vb = tid >> 9;

  __shared__ float stA[U_DIM];
  __shared__ float stB[U_DIM];
  __shared__ float pot_sh[U_DIM];
  __shared__ float pbest[1024];
  __shared__ unsigned short pidx[1024];

  const float* potb = pot + (size_t)b * T_DIM * U_DIM;

  if (vb == 0) {
    stA[u] = potb[u];              // state_0 = potentials[:,0]
  } else {
    pot_sh[u] = potb[U_DIM + u];   // potentials[:,1] ready for t=1
  }
  __syncthreads();

  float* cur = stA;
  float* nxt = stB;
  const float* trRow = trT + (size_t)u * U_DIM + (vb << 8);

  for (int t = 1; t < T_DIM; ++t) {
    // prefetch next step's potentials while we compute (vb==1 threads)
    float pn = 0.f;
    if (vb == 1 && t + 1 < T_DIM) pn = potb[(size_t)(t + 1) * U_DIM + u];

    float best = -3.402823466e38f;
    int bi = 0;
    const float4* tr4 = (const float4*)trRow;
    const float4* st4 = (const float4*)(cur + (vb << 8));
#pragma unroll 8
    for (int q = 0; q < 64; ++q) {
      float4 trv = tr4[q];
      float4 stv = st4[q];
      int vbase = (vb << 8) + (q << 2);
      float s0 = stv.x + trv.x;
      float s1 = stv.y + trv.y;
      float s2 = stv.z + trv.z;
      float s3 = stv.w + trv.w;
      if (s0 > best) { best = s0; bi = vbase; }
      if (s1 > best) { best = s1; bi = vbase + 1; }
      if (s2 > best) { best = s2; bi = vbase + 2; }
      if (s3 > best) { best = s3; bi = vbase + 3; }
    }
    pbest[tid] = best;
    pidx[tid] = (unsigned short)bi;
    __syncthreads();

    if (vb == 0) {
      float b0 = pbest[tid];
      float b1 = pbest[tid + 512];
      int i0 = pidx[tid];
      int i1 = pidx[tid + 512];
      float bb = b0;
      int ii = i0;
      if (b1 > b0) { bb = b1; ii = i1; }   // vb1 indices all larger: '>' keeps first-max
      nxt[u] = bb + pot_sh[u];
      bp[(size_t)(t - 1) * (B_DIM * U_DIM) + (size_t)b * U_DIM + u] =
          (unsigned short)ii;
    }
    __syncthreads();
    if (vb == 1 && t + 1 < T_DIM) pot_sh[u] = pn;

    float* tmp = cur; cur = nxt; nxt = tmp;
  }

  // argmax over final state (tie -> lowest u, matching jnp.argmax)
  if (vb == 0) {
    pbest[u] = cur[u];
    pidx[u] = (unsigned short)u;
  }
  __syncthreads();
  for (int s = 256; s > 0; s >>= 1) {
    if (tid < s) {
      float a = pbest[tid], c = pbest[tid + s];
      int ia = pidx[tid], ic = pidx[tid + s];
      if (c > a || (c == a && ic < ia)) { pbest[tid] = c; pidx[tid] = (unsigned short)ic; }
    }
    __syncthreads();
  }
  int tag = pidx[0];

  // backtrack (serial dependent chain; parallel across batches via blocks)
  if (tid == 0) {
    outv[(size_t)b * T_DIM + (T_DIM - 1)] = (float)tag;
    for (int t = T_DIM - 1; t >= 1; --t) {
      tag = bp[(size_t)(t - 1) * (B_DIM * U_DIM) + (size_t)b * U_DIM + tag];
      outv[(size_t)b * T_DIM + (t - 1)] = (float)tag;
    }
  }
}

// ---------------------------------------------------------------------------
extern "C" void kernel_launch(void* const* d_in, const int* in_sizes, int n_in,
                              void* d_out, int out_size, void* d_ws, size_t ws_size,
                              hipStream_t stream)
{
  const float* x    = (const float*)d_in[0];
  const float* W    = (const float*)d_in[1];
  const float* bias = (const float*)d_in[2];
  const float* tr   = (const float*)d_in[3];
  const float* lb   = (const float*)d_in[4];
  const float* rb   = (const float*)d_in[5];

  float* out = (float*)d_out;
  float* out_v   = out;                                      // (B,T) viterbi tags
  float* out_pot = out + (size_t)B_DIM * T_DIM;              // (B,T,U) potentials
  float* out_seq = out_pot + (size_t)B_DIM * T_DIM * U_DIM;  // (B,) seq lengths
  float* out_tr  = out_seq + B_DIM;                          // (U,U) transitions

  float* trT = (float*)d_ws;                                 // 1 MB transposed Tr
  unsigned short* bp =
      (unsigned short*)((char*)d_ws + (size_t)U_DIM * U_DIM * sizeof(float));

  hipLaunchKernelGGL(aux_kernel, dim3(1024), dim3(256), 0, stream,
                     tr, out_tr, trT, out_seq);
  hipLaunchKernelGGL(gemm_kernel, dim3(M_DIM / BM, U_DIM / BN), dim3(256), 0,
                     stream, x, W, bias, lb, rb, out_pot);
  hipLaunchKernelGGL(scan_kernel, dim3(B_DIM), dim3(1024), 0, stream,
                     out_pot, trT, bp, out_v);
}

// Round 2
// 18543.970 us; speedup vs baseline: 3.1985x; 3.1985x over previous
//
#include <hip/hip_runtime.h>
#include <cstddef>

#define U_DIM 512
#define T_DIM 2048
#define B_DIM 32
#define F_DIM 1024
#define M_DIM (B_DIM * T_DIM)
#define NBLK 8               // blocks per batch
#define UB (U_DIM / NBLK)    // 64 u-states per block

// ---------------------------------------------------------------------------
// GEMM: potentials[m][n] = sum_k x[m][k]*W[k][n] + b[n] (+ boundary at t=0/T-1)
// fp32 vector-ALU (no fp32 MFMA on CDNA4). 128x64 tile, 256 threads, 8x4 micro.
// (unchanged from R1 — known good, ~1.2 ms)
// ---------------------------------------------------------------------------
#define BM 128
#define BN 64
#define BK 16

__global__ __launch_bounds__(256) void gemm_kernel(
    const float* __restrict__ x, const float* __restrict__ W,
    const float* __restrict__ bias, const float* __restrict__ lb,
    const float* __restrict__ rb, float* __restrict__ out)
{
  __shared__ float As[BK][BM + 4];
  __shared__ float Bs[BK][BN];
  const int m0 = blockIdx.x * BM;
  const int n0 = blockIdx.y * BN;
  const int tid = threadIdx.x;
  const int tx = tid & 15;
  const int ty = tid >> 4;

  float acc[8][4];
#pragma unroll
  for (int i = 0; i < 8; ++i)
#pragma unroll
    for (int j = 0; j < 4; ++j) acc[i][j] = 0.f;

  for (int k0 = 0; k0 < F_DIM; k0 += BK) {
#pragma unroll
    for (int i = 0; i < 2; ++i) {
      int id = i * 256 + tid;
      int row = id >> 2;
      int c4 = (id & 3) << 2;
      float4 a = *(const float4*)(x + (size_t)(m0 + row) * F_DIM + k0 + c4);
      As[c4 + 0][row] = a.x;
      As[c4 + 1][row] = a.y;
      As[c4 + 2][row] = a.z;
      As[c4 + 3][row] = a.w;
    }
    {
      int krow = tid >> 4;
      int c4 = (tid & 15) << 2;
      *(float4*)(&Bs[krow][c4]) =
          *(const float4*)(W + (size_t)(k0 + krow) * U_DIM + n0 + c4);
    }
    __syncthreads();
#pragma unroll
    for (int k = 0; k < BK; ++k) {
      float a[8], bb[4];
#pragma unroll
      for (int i = 0; i < 8; ++i) a[i] = As[k][ty * 8 + i];
#pragma unroll
      for (int j = 0; j < 4; ++j) bb[j] = Bs[k][tx * 4 + j];
#pragma unroll
      for (int i = 0; i < 8; ++i)
#pragma unroll
        for (int j = 0; j < 4; ++j) acc[i][j] += a[i] * bb[j];
    }
    __syncthreads();
  }

#pragma unroll
  for (int i = 0; i < 8; ++i) {
    int m = m0 + ty * 8 + i;
    int t = m & (T_DIM - 1);
    float4 o;
#pragma unroll
    for (int j = 0; j < 4; ++j) {
      int n = n0 + tx * 4 + j;
      float v = acc[i][j] + bias[n];
      if (t == 0) v += lb[n];
      if (t == T_DIM - 1) v += rb[n];
      ((float*)&o)[j] = v;
    }
    *(float4*)(out + (size_t)m * U_DIM + n0 + tx * 4) = o;
  }
}

// ---------------------------------------------------------------------------
// aux: copy transitions to output tail, build transposed TrT[u][v] in ws,
// write sequence_lengths.
// ---------------------------------------------------------------------------
__global__ void aux_kernel(const float* __restrict__ tr, float* __restrict__ out_tr,
                           float* __restrict__ trT, float* __restrict__ seqlen)
{
  int idx = blockIdx.x * blockDim.x + threadIdx.x;
  if (idx < U_DIM * U_DIM) {
    float v = tr[idx];
    out_tr[idx] = v;
    int r = idx >> 9;   // v
    int c = idx & 511;  // u
    trT[(size_t)c * U_DIM + r] = v;
  }
  if (idx < B_DIM) seqlen[idx] = (float)T_DIM;
}

// zero the per-(batch,step) arrival counters (ws is poisoned every launch)
__global__ void init_kernel(unsigned int* __restrict__ cnt)
{
  int i = blockIdx.x * blockDim.x + threadIdx.x;
  if (i < B_DIM * T_DIM) cnt[i] = 0u;
}

// ---------------------------------------------------------------------------
// Viterbi forward scan, full-chip: 256 blocks = 8 u-slice blocks x 32 batches.
// blockIdx: b = blk & 31 (batch-mates share blk%8 -> same-XCD heuristic),
//           j = blk >> 5 (u-slice).
// 512 threads: u_local = tid>>3 (64 u's), vseg = tid&7.
// Thread's v set = { vseg*4 + 32m + c : m=0..15, c=0..3 } -> ascending order,
// LDS state reads broadcast + conflict-free. trT slice held in 16 float4 regs
// per thread (loaded once; zero per-step transition traffic).
// Cross-block per-batch sync: state double-buffer in ws + arrival counters
// (threadfence + device atomicAdd release / acquire-load spin).
// ---------------------------------------------------------------------------
__global__ __launch_bounds__(512) void scan_kernel(
    const float* __restrict__ pot, const float* __restrict__ trT,
    float* __restrict__ stateBuf,        // [2][B][U]
    unsigned int* __restrict__ cnt,      // [B][T]
    unsigned short* __restrict__ bp,     // [T-1][B][U]
    float* __restrict__ outv)            // [B][T]
{
  const int blk = blockIdx.x;
  const int b = blk & (B_DIM - 1);
  const int j = blk >> 5;
  const int tid = threadIdx.x;
  const int u_local = tid >> 3;
  const int vseg = tid & 7;
  const int u = j * UB + u_local;

  __shared__ float sh_state[U_DIM];
  __shared__ float sh_v[U_DIM];
  __shared__ int sh_i[U_DIM];

  // load this thread's transition slice into registers (once)
  float4 trreg[16];
  const float* trRow = trT + (size_t)u * U_DIM;
#pragma unroll
  for (int m = 0; m < 16; ++m)
    trreg[m] = *(const float4*)(trRow + vseg * 4 + m * 32);

  const float* potb = pot + (size_t)b * T_DIM * U_DIM;

  for (int t = 1; t < T_DIM; ++t) {
    // wait for all 8 blocks of this batch to have published state t-1
    if (t > 1) {
      if (tid == 0) {
        while (__hip_atomic_load(&cnt[b * T_DIM + (t - 1)], __ATOMIC_ACQUIRE,
                                 __HIP_MEMORY_SCOPE_AGENT) < NBLK) {}
      }
      __syncthreads();
    }
    // stage previous state into LDS (t==1: state0 = potentials[:,0])
    const float* src = (t == 1)
        ? potb
        : stateBuf + (size_t)((t - 1) & 1) * B_DIM * U_DIM + (size_t)b * U_DIM;
    sh_state[tid] = src[tid];
    __syncthreads();

    float p_u = potb[(size_t)t * U_DIM + u];  // 8-lane broadcast

    float best = -3.402823466e38f;
    int bi = 0;
#pragma unroll
    for (int m = 0; m < 16; ++m) {
      float4 st = *(const float4*)(&sh_state[vseg * 4 + m * 32]);
      float4 trv = trreg[m];
      int vbase = vseg * 4 + m * 32;
      float s0 = st.x + trv.x;
      float s1 = st.y + trv.y;
      float s2 = st.z + trv.z;
      float s3 = st.w + trv.w;
      if (s0 > best) { best = s0; bi = vbase; }
      if (s1 > best) { best = s1; bi = vbase + 1; }
      if (s2 > best) { best = s2; bi = vbase + 2; }
      if (s3 > best) { best = s3; bi = vbase + 3; }
    }
    // combine the 8 vseg partials (lanes u_local*8 .. +7), first-max tie rule
#pragma unroll
    for (int d = 1; d < 8; d <<= 1) {
      float ob = __shfl_xor(best, d, 64);
      int oi = __shfl_xor(bi, d, 64);
      if (ob > best || (ob == best && oi < bi)) { best = ob; bi = oi; }
    }
    if (vseg == 0) {
      float ns = best + p_u;
      stateBuf[(size_t)(t & 1) * B_DIM * U_DIM + (size_t)b * U_DIM + u] = ns;
      bp[(size_t)(t - 1) * (B_DIM * U_DIM) + (size_t)b * U_DIM + u] =
          (unsigned short)bi;
    }
    __syncthreads();  // all writes of this block issued (vmcnt drained)
    if (tid == 0) {
      __threadfence();  // device-scope release of state/bp writes
      atomicAdd(&cnt[b * T_DIM + t], 1u);
    }
  }

  // block j==0 of each batch: final argmax + backtrack
  if (j == 0) {
    if (tid == 0) {
      while (__hip_atomic_load(&cnt[b * T_DIM + (T_DIM - 1)], __ATOMIC_ACQUIRE,
                               __HIP_MEMORY_SCOPE_AGENT) < NBLK) {}
    }
    __syncthreads();
    sh_v[tid] = stateBuf[(size_t)1 * B_DIM * U_DIM + (size_t)b * U_DIM + tid];
    sh_i[tid] = tid;
    __syncthreads();
    for (int s = 256; s > 0; s >>= 1) {
      if (tid < s) {
        float a = sh_v[tid], c = sh_v[tid + s];
        int ia = sh_i[tid], ic = sh_i[tid + s];
        if (c > a || (c == a && ic < ia)) { sh_v[tid] = c; sh_i[tid] = ic; }
      }
      __syncthreads();
    }
    if (tid == 0) {
      int tag = sh_i[0];
      outv[(size_t)b * T_DIM + (T_DIM - 1)] = (float)tag;
      for (int t = T_DIM - 1; t >= 1; --t) {
        tag = bp[(size_t)(t - 1) * (B_DIM * U_DIM) + (size_t)b * U_DIM + tag];
        outv[(size_t)b * T_DIM + (t - 1)] = (float)tag;
      }
    }
  }
}

// ---------------------------------------------------------------------------
extern "C" void kernel_launch(void* const* d_in, const int* in_sizes, int n_in,
                              void* d_out, int out_size, void* d_ws, size_t ws_size,
                              hipStream_t stream)
{
  const float* x    = (const float*)d_in[0];
  const float* W    = (const float*)d_in[1];
  const float* bias = (const float*)d_in[2];
  const float* tr   = (const float*)d_in[3];
  const float* lb   = (const float*)d_in[4];
  const float* rb   = (const float*)d_in[5];

  float* out = (float*)d_out;
  float* out_v   = out;                                      // (B,T) viterbi tags
  float* out_pot = out + (size_t)B_DIM * T_DIM;              // (B,T,U) potentials
  float* out_seq = out_pot + (size_t)B_DIM * T_DIM * U_DIM;  // (B,) seq lengths
  float* out_tr  = out_seq + B_DIM;                          // (U,U) transitions

  // ws layout
  float* trT = (float*)d_ws;                                   // 1 MB
  float* stateBuf = trT + (size_t)U_DIM * U_DIM;               // 128 KB
  unsigned int* cnt = (unsigned int*)(stateBuf + 2 * B_DIM * U_DIM);  // 256 KB
  unsigned short* bp = (unsigned short*)(cnt + B_DIM * T_DIM);        // ~64 MB

  hipLaunchKernelGGL(init_kernel, dim3((B_DIM * T_DIM + 255) / 256), dim3(256),
                     0, stream, cnt);
  hipLaunchKernelGGL(aux_kernel, dim3(1024), dim3(256), 0, stream,
                     tr, out_tr, trT, out_seq);
  hipLaunchKernelGGL(gemm_kernel, dim3(M_DIM / BM, U_DIM / BN), dim3(256), 0,
                     stream, x, W, bias, lb, rb, out_pot);
  hipLaunchKernelGGL(scan_kernel, dim3(NBLK * B_DIM), dim3(512), 0, stream,
                     out_pot, trT, stateBuf, cnt, bp, out_v);
}